// Round 8
// baseline (390.165 us; speedup 1.0000x reference)
//
#include <hip/hip_runtime.h>

// Problem constants (fixed by the reference file)
#define NODES_C 65536   // N*N, N=256
#define B_C     16
#define E_C     1048576 // NODES*16
#define K_C     5

#define MAXE    2048    // LDS CSR-segment cap per 64-node step block
#define CAP_D   8192    // per-bucket LDS cap in k_sortb (avg 4096, 50+ sigma safe)

typedef unsigned long long u64;

__device__ inline unsigned short f2bf(float f) {   // RNE float->bf16
    unsigned u = __float_as_uint(f);
    u += 0x7FFFu + ((u >> 16) & 1u);
    return (unsigned short)(u >> 16);
}

// ---------------------------------------------------------------------------
// Build kernel A: 256-bin histogram of dst>>8
__global__ __launch_bounds__(256) void k_hist(
    const int* __restrict__ dst, int* __restrict__ hist)
{
    __shared__ int h[256];
    int tid = threadIdx.x;
    h[tid] = 0;
    __syncthreads();
    int e0 = blockIdx.x * 1024;
    #pragma unroll
    for (int j = 0; j < 4; ++j)
        atomicAdd(&h[((unsigned)dst[e0 + j * 256 + tid]) >> 8], 1);
    __syncthreads();
    atomicAdd(&hist[tid], h[tid]);
}

// ---------------------------------------------------------------------------
// Build kernel B: exclusive scan of hist256 -> base, fill
__global__ __launch_bounds__(256) void k_scan256(
    const int* __restrict__ hist, int* __restrict__ base, int* __restrict__ fill)
{
    __shared__ int s[256];
    int t = threadIdx.x;
    s[t] = hist[t];
    __syncthreads();
    for (int off = 1; off < 256; off <<= 1) {
        int v = s[t];
        int a = (t >= off) ? s[t - off] : 0;
        __syncthreads();
        s[t] = v + a;
        __syncthreads();
    }
    int ex = (t == 0) ? 0 : s[t - 1];
    base[t] = ex;
    fill[t] = ex;
}

// ---------------------------------------------------------------------------
// Build kernel C: compute w, pack {w | dst&255 | src}, bucket by dst>>8 into
// csr (bucket-clustered, run-contiguous writes). 256 blocks x 4096 edges.
__global__ __launch_bounds__(256) void k_bucket(
    const int* __restrict__ src, const int* __restrict__ dst,
    const float* __restrict__ dist, const float* __restrict__ coeffs,
    int* __restrict__ fill, u64* __restrict__ csr)
{
    __shared__ int hist[256];
    __shared__ int scan[256];
    __shared__ int exs[256];
    __shared__ int gpos[256];
    __shared__ int lfill[256];
    __shared__ u64 stage[4096];

    int tid = threadIdx.x;
    hist[tid] = 0;
    __syncthreads();

    float c0 = coeffs[0], c1 = coeffs[1], c2 = coeffs[2], c3 = coeffs[3], c4 = coeffs[4];
    int e0 = blockIdx.x * 4096;
    u64 pk[16];
    int bk[16];
    #pragma unroll
    for (int j = 0; j < 16; ++j) {
        int e = e0 + j * 256 + tid;
        unsigned s = (unsigned)src[e];
        unsigned d = (unsigned)dst[e];
        const float* dd = dist + (size_t)e * K_C;
        float wv = dd[0]*c0 + dd[1]*c1 + dd[2]*c2 + dd[3]*c3 + dd[4]*c4;
        pk[j] = ((u64)__float_as_uint(wv) << 32) | ((d & 255u) << 16) | s;
        bk[j] = (int)(d >> 8);
        atomicAdd(&hist[bk[j]], 1);
    }
    __syncthreads();

    scan[tid] = hist[tid];
    __syncthreads();
    for (int off = 1; off < 256; off <<= 1) {
        int v = scan[tid];
        int a = (tid >= off) ? scan[tid - off] : 0;
        __syncthreads();
        scan[tid] = v + a;
        __syncthreads();
    }
    exs[tid]   = scan[tid] - hist[tid];               // local exclusive base
    gpos[tid]  = atomicAdd(&fill[tid], hist[tid]);    // absolute run start
    lfill[tid] = 0;
    __syncthreads();

    #pragma unroll
    for (int j = 0; j < 16; ++j) {
        int b = bk[j];
        int p = exs[b] + atomicAdd(&lfill[b], 1);
        stage[p] = pk[j];
    }
    __syncthreads();

    int c = hist[tid], g = gpos[tid], lb = exs[tid];
    for (int i = 0; i < c; ++i) csr[g + i] = stage[lb + i];
}

// ---------------------------------------------------------------------------
// Build kernel D: one block per bucket. In-place counting sort of the bucket
// by dst&255 (LDS), coalesced write-back, emits row_start for its 256 nodes.
__global__ __launch_bounds__(256) void k_sortb(
    const int* __restrict__ base, const int* __restrict__ hist,
    u64* __restrict__ csr, int* __restrict__ row_start)
{
    __shared__ u64 stage[CAP_D];
    __shared__ int h[256];
    __shared__ int sc[256];
    __shared__ int lf[256];

    int b = blockIdx.x, tid = threadIdx.x;
    int b0 = base[b];
    int len = hist[b];

    h[tid] = 0;
    __syncthreads();
    for (int i = tid; i < len; i += 256)
        atomicAdd(&h[(int)((csr[b0 + i] >> 16) & 255u)], 1);
    __syncthreads();

    sc[tid] = h[tid];
    __syncthreads();
    for (int off = 1; off < 256; off <<= 1) {
        int v = sc[tid];
        int a = (tid >= off) ? sc[tid - off] : 0;
        __syncthreads();
        sc[tid] = v + a;
        __syncthreads();
    }
    int ex = sc[tid] - h[tid];
    row_start[b * 256 + tid] = b0 + ex;
    lf[tid] = 0;
    __syncthreads();

    for (int i = tid; i < len; i += 256) {
        u64 m = csr[b0 + i];
        int dl = (int)((m >> 16) & 255u);
        int p = (sc[dl] - h[dl]) + atomicAdd(&lf[dl], 1);
        stage[p] = m;
    }
    __syncthreads();
    for (int i = tid; i < len; i += 256) csr[b0 + i] = stage[i];
    if (b == 255 && tid == 255) row_start[NODES_C] = b0 + len;  // == E
}

// ---------------------------------------------------------------------------
// Kernel: init node-major f32 state + bf16 gather mirror
__global__ __launch_bounds__(256) void k_init(
    const float* __restrict__ x_in, float* __restrict__ xf,
    unsigned short* __restrict__ xb)
{
    int tid = blockIdx.x * 256 + threadIdx.x;   // tid = b*N + n
    int b = tid >> 16;                          // N = 65536 = 2^16
    int n = tid & 0xFFFF;
    float v = x_in[tid];
    xf[((size_t)n << 4) + b] = v;
    xb[((size_t)n << 4) + b] = f2bf(v);
}

// ---------------------------------------------------------------------------
// Step kernel. Gathers read the bf16 mirror (the ONLY cached data: all
// streaming accesses use non-temporal hints so L2 stays mirror-resident).
// Block = 64 nodes; thread = (node, quad). Row loop unrolled x16.
__global__ __launch_bounds__(256) void k_step(
    const int* __restrict__ row_start, const u64* __restrict__ csr,
    float* __restrict__ xf, const unsigned short* __restrict__ xbc,
    unsigned short* __restrict__ xbn, float* __restrict__ out,
    const float* __restrict__ dt_p, size_t TN, int tstep)
{
    __shared__ u64 meta[MAXE + 16];
    __shared__ int rows[65];
    __shared__ float tile[64][17];

    int tid = threadIdx.x;
    int n0  = blockIdx.x * 64;

    // L2 warm: 16KB slice of the current mirror per block (cached loads).
    {
        const uint4* pf = (const uint4*)xbc + ((size_t)(blockIdx.x >> 3) << 10);
        unsigned acc = 0;
        #pragma unroll
        for (int k = 0; k < 4; ++k) {
            uint4 v = pf[k * 256 + tid];
            acc ^= v.x ^ v.w;
        }
        asm volatile("" :: "v"(acc));   // keep loads alive, no side effect
    }

    int seg0   = row_start[n0];
    int segLen = row_start[n0 + 64] - seg0;
    if (tid < 65) rows[tid] = row_start[n0 + tid];
    bool lds_ok = (segLen <= MAXE);
    if (lds_ok) {
        for (int i = tid; i < segLen; i += 256)
            meta[i] = __builtin_nontemporal_load(&csr[seg0 + i]);
        if (tid < 16) meta[segLen + tid] = 0;   // zero pad for the tail over-read
    }
    __syncthreads();

    int ln = tid >> 2;            // local node 0..63
    int q  = tid & 3;             // batch quad
    int n  = n0 + ln;
    int r0 = rows[ln]     - seg0;
    int r1 = rows[ln + 1] - seg0;

    float ax = 0.f, ay = 0.f, az = 0.f, aw = 0.f;
    const unsigned short* xq = xbc + (q << 2);

    if (lds_ok) {
        for (int i = r0; i < r1; i += 16) {
            float wv[16];
            uint2 rv[16];
            #pragma unroll
            for (int j = 0; j < 16; ++j) {
                u64 m = meta[i + j];                     // LDS
                int s = ((int)(unsigned)m) & 0xFFFF;
                wv[j] = (i + j < r1) ? __uint_as_float((unsigned)(m >> 32)) : 0.f;
                rv[j] = *(const uint2*)(xq + ((size_t)s << 4));
            }
            #pragma unroll
            for (int j = 0; j < 16; ++j) {
                float v0 = __uint_as_float(rv[j].x << 16);
                float v1 = __uint_as_float(rv[j].x & 0xFFFF0000u);
                float v2 = __uint_as_float(rv[j].y << 16);
                float v3 = __uint_as_float(rv[j].y & 0xFFFF0000u);
                ax = fmaf(wv[j], v0, ax);
                ay = fmaf(wv[j], v1, ay);
                az = fmaf(wv[j], v2, az);
                aw = fmaf(wv[j], v3, aw);
            }
        }
    } else {
        for (int i = r0; i < r1; i += 16) {
            u64 m[16];
            #pragma unroll
            for (int j = 0; j < 16; ++j)
                m[j] = __builtin_nontemporal_load(&csr[seg0 + i + j]);
            float wv[16];
            uint2 rv[16];
            #pragma unroll
            for (int j = 0; j < 16; ++j) {
                int s = ((int)(unsigned)m[j]) & 0xFFFF;
                wv[j] = (i + j < r1) ? __uint_as_float((unsigned)(m[j] >> 32)) : 0.f;
                rv[j] = *(const uint2*)(xq + ((size_t)s << 4));
            }
            #pragma unroll
            for (int j = 0; j < 16; ++j) {
                float v0 = __uint_as_float(rv[j].x << 16);
                float v1 = __uint_as_float(rv[j].x & 0xFFFF0000u);
                float v2 = __uint_as_float(rv[j].y << 16);
                float v3 = __uint_as_float(rv[j].y & 0xFFFF0000u);
                ax = fmaf(wv[j], v0, ax);
                ay = fmaf(wv[j], v1, ay);
                az = fmaf(wv[j], v2, az);
                aw = fmaf(wv[j], v3, aw);
            }
        }
    }

    float dt = dt_p[0];
    size_t own = (((size_t)n) << 4) + (q << 2);
    float4 xo;
    xo.x = __builtin_nontemporal_load(xf + own + 0);
    xo.y = __builtin_nontemporal_load(xf + own + 1);
    xo.z = __builtin_nontemporal_load(xf + own + 2);
    xo.w = __builtin_nontemporal_load(xf + own + 3);
    xo.x = fmaf(dt, ax, xo.x);
    xo.y = fmaf(dt, ay, xo.y);
    xo.z = fmaf(dt, az, xo.z);
    xo.w = fmaf(dt, aw, xo.w);
    __builtin_nontemporal_store(xo.x, xf + own + 0);
    __builtin_nontemporal_store(xo.y, xf + own + 1);
    __builtin_nontemporal_store(xo.z, xf + own + 2);
    __builtin_nontemporal_store(xo.w, xf + own + 3);

    unsigned lo = ((unsigned)f2bf(xo.x)) | (((unsigned)f2bf(xo.y)) << 16);
    unsigned hi = ((unsigned)f2bf(xo.z)) | (((unsigned)f2bf(xo.w)) << 16);
    __builtin_nontemporal_store(lo, (unsigned*)(xbn + own));
    __builtin_nontemporal_store(hi, (unsigned*)(xbn + own) + 1);

    // LDS transpose: 64 nodes x 16 batches -> coalesced NT out writes
    int c0i = q << 2;
    tile[ln][c0i + 0] = xo.x;
    tile[ln][c0i + 1] = xo.y;
    tile[ln][c0i + 2] = xo.z;
    tile[ln][c0i + 3] = xo.w;
    __syncthreads();
    int wb  = tid >> 4;               // batch 0..15
    int wn0 = (tid & 15) << 2;        // local node 0,4,..,60
    float* op = out + (size_t)wb * TN + (size_t)tstep * NODES_C + n0 + wn0;
    __builtin_nontemporal_store(tile[wn0 + 0][wb], op + 0);
    __builtin_nontemporal_store(tile[wn0 + 1][wb], op + 1);
    __builtin_nontemporal_store(tile[wn0 + 2][wb], op + 2);
    __builtin_nontemporal_store(tile[wn0 + 3][wb], op + 3);
}

// ---------------------------------------------------------------------------
extern "C" void kernel_launch(void* const* d_in, const int* in_sizes, int n_in,
                              void* d_out, int out_size, void* d_ws, size_t ws_size,
                              hipStream_t stream)
{
    const float* x_in   = (const float*)d_in[0];
    // d_in[1] = points (unused by the reference computation)
    const int*   eidx   = (const int*)d_in[2];
    const float* dt_p   = (const float*)d_in[3];
    // d_in[4] = num_blocks (T derived from out_size instead)
    const float* dist   = (const float*)d_in[5];
    const float* coeffs = (const float*)d_in[6];

    const int* src = eidx;          // edge_index[0]
    const int* dst = eidx + E_C;    // edge_index[1]
    float* out = (float*)d_out;

    // workspace layout (~17 MB)
    char* ws = (char*)d_ws;
    int*   row_start = (int*)(ws + 0);                     // 256 KB + 4
    int*   hist256   = (int*)(ws + (512u << 10));          // 1 KB
    int*   base256   = (int*)(ws + (516u << 10));          // 1 KB
    int*   fill256   = (int*)(ws + (520u << 10));          // 1 KB
    u64*   csr       = (u64*)(ws + (1u  << 20));           // 8 MB
    float* xf        = (float*)(ws + (9u  << 20));         // 4 MB f32 state
    unsigned short* xb0 = (unsigned short*)(ws + (13u << 20)); // 2 MB bf16 mirror
    unsigned short* xb1 = (unsigned short*)(ws + (15u << 20)); // 2 MB bf16 mirror

    int T = out_size / (B_C * NODES_C);          // = 20
    size_t TN = (size_t)T * NODES_C;

    hipMemsetAsync(hist256, 0, 256 * sizeof(int), stream);
    k_hist   <<<E_C / 1024, 256, 0, stream>>>(dst, hist256);
    k_scan256<<<1, 256, 0, stream>>>(hist256, base256, fill256);
    k_bucket <<<E_C / 4096, 256, 0, stream>>>(src, dst, dist, coeffs, fill256, csr);
    k_sortb  <<<256, 256, 0, stream>>>(base256, hist256, csr, row_start);
    k_init   <<<(NODES_C * B_C) / 256, 256, 0, stream>>>(x_in, xf, xb0);

    unsigned short* xbufs[2] = { xb0, xb1 };
    for (int t = 0; t < T; ++t) {
        k_step<<<(NODES_C * B_C / 4) / 256, 256, 0, stream>>>(
            row_start, csr, xf, xbufs[t & 1], xbufs[(t + 1) & 1],
            out, dt_p, TN, t);
    }
}

// Round 9
// 291.147 us; speedup vs baseline: 1.3401x; 1.3401x over previous
//
#include <hip/hip_runtime.h>

// Problem constants (fixed by the reference file)
#define NODES_C 65536   // N*N, N=256
#define B_C     16
#define E_C     1048576 // NODES*16
#define K_C     5

#define MAXE    1024    // LDS CSR-segment cap per 32-node step block (avg 512, 23 sigma)
#define CAP_D   8192    // per-bucket LDS cap in k_sortb (avg 4096, 50+ sigma safe)

typedef unsigned long long u64;

__device__ inline unsigned short f2bf(float f) {   // RNE float->bf16
    unsigned u = __float_as_uint(f);
    u += 0x7FFFu + ((u >> 16) & 1u);
    return (unsigned short)(u >> 16);
}

// ---------------------------------------------------------------------------
// Build kernel A: 256-bin histogram of dst>>8
__global__ __launch_bounds__(256) void k_hist(
    const int* __restrict__ dst, int* __restrict__ hist)
{
    __shared__ int h[256];
    int tid = threadIdx.x;
    h[tid] = 0;
    __syncthreads();
    int e0 = blockIdx.x * 1024;
    #pragma unroll
    for (int j = 0; j < 4; ++j)
        atomicAdd(&h[((unsigned)dst[e0 + j * 256 + tid]) >> 8], 1);
    __syncthreads();
    atomicAdd(&hist[tid], h[tid]);
}

// ---------------------------------------------------------------------------
// Build kernel B: exclusive scan of hist256 -> base, fill
__global__ __launch_bounds__(256) void k_scan256(
    const int* __restrict__ hist, int* __restrict__ base, int* __restrict__ fill)
{
    __shared__ int s[256];
    int t = threadIdx.x;
    s[t] = hist[t];
    __syncthreads();
    for (int off = 1; off < 256; off <<= 1) {
        int v = s[t];
        int a = (t >= off) ? s[t - off] : 0;
        __syncthreads();
        s[t] = v + a;
        __syncthreads();
    }
    int ex = (t == 0) ? 0 : s[t - 1];
    base[t] = ex;
    fill[t] = ex;
}

// ---------------------------------------------------------------------------
// Build kernel C: compute w, pack {w | dst&255 | src}, bucket by dst>>8 into
// csr (bucket-clustered, run-contiguous writes). 256 blocks x 4096 edges.
__global__ __launch_bounds__(256) void k_bucket(
    const int* __restrict__ src, const int* __restrict__ dst,
    const float* __restrict__ dist, const float* __restrict__ coeffs,
    int* __restrict__ fill, u64* __restrict__ csr)
{
    __shared__ int hist[256];
    __shared__ int scan[256];
    __shared__ int exs[256];
    __shared__ int gpos[256];
    __shared__ int lfill[256];
    __shared__ u64 stage[4096];

    int tid = threadIdx.x;
    hist[tid] = 0;
    __syncthreads();

    float c0 = coeffs[0], c1 = coeffs[1], c2 = coeffs[2], c3 = coeffs[3], c4 = coeffs[4];
    int e0 = blockIdx.x * 4096;
    u64 pk[16];
    int bk[16];
    #pragma unroll
    for (int j = 0; j < 16; ++j) {
        int e = e0 + j * 256 + tid;
        unsigned s = (unsigned)src[e];
        unsigned d = (unsigned)dst[e];
        const float* dd = dist + (size_t)e * K_C;
        float wv = dd[0]*c0 + dd[1]*c1 + dd[2]*c2 + dd[3]*c3 + dd[4]*c4;
        pk[j] = ((u64)__float_as_uint(wv) << 32) | ((d & 255u) << 16) | s;
        bk[j] = (int)(d >> 8);
        atomicAdd(&hist[bk[j]], 1);
    }
    __syncthreads();

    scan[tid] = hist[tid];
    __syncthreads();
    for (int off = 1; off < 256; off <<= 1) {
        int v = scan[tid];
        int a = (tid >= off) ? scan[tid - off] : 0;
        __syncthreads();
        scan[tid] = v + a;
        __syncthreads();
    }
    exs[tid]   = scan[tid] - hist[tid];               // local exclusive base
    gpos[tid]  = atomicAdd(&fill[tid], hist[tid]);    // absolute run start
    lfill[tid] = 0;
    __syncthreads();

    #pragma unroll
    for (int j = 0; j < 16; ++j) {
        int b = bk[j];
        int p = exs[b] + atomicAdd(&lfill[b], 1);
        stage[p] = pk[j];
    }
    __syncthreads();

    int c = hist[tid], g = gpos[tid], lb = exs[tid];
    for (int i = 0; i < c; ++i) csr[g + i] = stage[lb + i];
}

// ---------------------------------------------------------------------------
// Build kernel D: one block per bucket. In-place counting sort of the bucket
// by dst&255 (LDS), coalesced write-back, emits row_start for its 256 nodes.
__global__ __launch_bounds__(256) void k_sortb(
    const int* __restrict__ base, const int* __restrict__ hist,
    u64* __restrict__ csr, int* __restrict__ row_start)
{
    __shared__ u64 stage[CAP_D];
    __shared__ int h[256];
    __shared__ int sc[256];
    __shared__ int lf[256];

    int b = blockIdx.x, tid = threadIdx.x;
    int b0 = base[b];
    int len = hist[b];

    h[tid] = 0;
    __syncthreads();
    for (int i = tid; i < len; i += 256)
        atomicAdd(&h[(int)((csr[b0 + i] >> 16) & 255u)], 1);
    __syncthreads();

    sc[tid] = h[tid];
    __syncthreads();
    for (int off = 1; off < 256; off <<= 1) {
        int v = sc[tid];
        int a = (tid >= off) ? sc[tid - off] : 0;
        __syncthreads();
        sc[tid] = v + a;
        __syncthreads();
    }
    int ex = sc[tid] - h[tid];
    row_start[b * 256 + tid] = b0 + ex;
    lf[tid] = 0;
    __syncthreads();

    for (int i = tid; i < len; i += 256) {
        u64 m = csr[b0 + i];
        int dl = (int)((m >> 16) & 255u);
        int p = (sc[dl] - h[dl]) + atomicAdd(&lf[dl], 1);
        stage[p] = m;
    }
    __syncthreads();
    for (int i = tid; i < len; i += 256) csr[b0 + i] = stage[i];
    if (b == 255 && tid == 255) row_start[NODES_C] = b0 + len;  // == E
}

// ---------------------------------------------------------------------------
// Kernel: init node-major f32 state + bf16 gather mirror
__global__ __launch_bounds__(256) void k_init(
    const float* __restrict__ x_in, float* __restrict__ xf,
    unsigned short* __restrict__ xb)
{
    int tid = blockIdx.x * 256 + threadIdx.x;   // tid = b*N + n
    int b = tid >> 16;                          // N = 65536 = 2^16
    int n = tid & 0xFFFF;
    float v = x_in[tid];
    xf[((size_t)n << 4) + b] = v;
    xb[((size_t)n << 4) + b] = f2bf(v);
}

// ---------------------------------------------------------------------------
// Step kernel, high-occupancy variant: 32-node blocks, 8 threads per node
// (each owns a batch PAIR, 4B of the bf16 mirror), 2048 blocks -> 32 waves/CU.
// 8 lanes/node coalesce to one 32B request per edge (unchanged), but 2x the
// waves keep 2x the gather instructions in flight machine-wide.
__global__ __launch_bounds__(256, 8) void k_step(
    const int* __restrict__ row_start, const u64* __restrict__ csr,
    float* __restrict__ xf, const unsigned short* __restrict__ xbc,
    unsigned short* __restrict__ xbn, float* __restrict__ out,
    const float* __restrict__ dt_p, size_t TN, int tstep)
{
    __shared__ u64 meta[MAXE + 8];
    __shared__ int rows[33];
    __shared__ float tile[32][17];

    int tid = threadIdx.x;
    int n0  = blockIdx.x * 32;

    if (tid < 33) rows[tid] = row_start[n0 + tid];
    __syncthreads();
    int seg0   = rows[0];
    int segLen = rows[32] - seg0;
    bool lds_ok = (segLen <= MAXE);
    if (lds_ok) {
        for (int i = tid; i < segLen; i += 256) meta[i] = csr[seg0 + i];
        if (tid < 8) meta[segLen + tid] = 0;   // zero pad for the tail over-read
    }
    __syncthreads();

    int ln = tid >> 3;            // local node 0..31
    int oc = tid & 7;             // batch pair 0..7
    int n  = n0 + ln;
    int r0 = rows[ln]     - seg0;
    int r1 = rows[ln + 1] - seg0;

    float a0 = 0.f, a1 = 0.f;
    const unsigned short* xq = xbc + (oc << 1);

    if (lds_ok) {
        for (int i = r0; i < r1; i += 8) {
            float wv[8];
            unsigned rv[8];
            #pragma unroll
            for (int j = 0; j < 8; ++j) {
                u64 m = meta[i + j];                     // LDS (8-lane broadcast)
                int s = ((int)(unsigned)m) & 0xFFFF;
                wv[j] = (i + j < r1) ? __uint_as_float((unsigned)(m >> 32)) : 0.f;
                rv[j] = *(const unsigned*)(xq + ((size_t)s << 4));
            }
            #pragma unroll
            for (int j = 0; j < 8; ++j) {
                a0 = fmaf(wv[j], __uint_as_float(rv[j] << 16), a0);
                a1 = fmaf(wv[j], __uint_as_float(rv[j] & 0xFFFF0000u), a1);
            }
        }
    } else {
        for (int i = r0; i < r1; i += 8) {
            u64 m[8];
            #pragma unroll
            for (int j = 0; j < 8; ++j) m[j] = csr[seg0 + i + j];
            float wv[8];
            unsigned rv[8];
            #pragma unroll
            for (int j = 0; j < 8; ++j) {
                int s = ((int)(unsigned)m[j]) & 0xFFFF;
                wv[j] = (i + j < r1) ? __uint_as_float((unsigned)(m[j] >> 32)) : 0.f;
                rv[j] = *(const unsigned*)(xq + ((size_t)s << 4));
            }
            #pragma unroll
            for (int j = 0; j < 8; ++j) {
                a0 = fmaf(wv[j], __uint_as_float(rv[j] << 16), a0);
                a1 = fmaf(wv[j], __uint_as_float(rv[j] & 0xFFFF0000u), a1);
            }
        }
    }

    float dt = dt_p[0];
    size_t own = (((size_t)n) << 4) + (oc << 1);
    float2 xo = *(const float2*)(xf + own);
    xo.x = fmaf(dt, a0, xo.x);
    xo.y = fmaf(dt, a1, xo.y);
    *(float2*)(xf + own) = xo;

    unsigned pk = ((unsigned)f2bf(xo.x)) | (((unsigned)f2bf(xo.y)) << 16);
    *(unsigned*)(xbn + own) = pk;

    // LDS transpose: 32 nodes x 16 batches -> coalesced out writes
    int c0i = oc << 1;
    tile[ln][c0i + 0] = xo.x;
    tile[ln][c0i + 1] = xo.y;
    __syncthreads();
    int wb = tid >> 4;                // batch 0..15
    int wn = (tid & 15) << 1;         // local node 0,2,..,30
    float2 ov;
    ov.x = tile[wn + 0][wb];
    ov.y = tile[wn + 1][wb];
    *(float2*)(out + (size_t)wb * TN + (size_t)tstep * NODES_C + n0 + wn) = ov;
}

// ---------------------------------------------------------------------------
extern "C" void kernel_launch(void* const* d_in, const int* in_sizes, int n_in,
                              void* d_out, int out_size, void* d_ws, size_t ws_size,
                              hipStream_t stream)
{
    const float* x_in   = (const float*)d_in[0];
    // d_in[1] = points (unused by the reference computation)
    const int*   eidx   = (const int*)d_in[2];
    const float* dt_p   = (const float*)d_in[3];
    // d_in[4] = num_blocks (T derived from out_size instead)
    const float* dist   = (const float*)d_in[5];
    const float* coeffs = (const float*)d_in[6];

    const int* src = eidx;          // edge_index[0]
    const int* dst = eidx + E_C;    // edge_index[1]
    float* out = (float*)d_out;

    // workspace layout (~17 MB)
    char* ws = (char*)d_ws;
    int*   row_start = (int*)(ws + 0);                     // 256 KB + 4
    int*   hist256   = (int*)(ws + (512u << 10));          // 1 KB
    int*   base256   = (int*)(ws + (516u << 10));          // 1 KB
    int*   fill256   = (int*)(ws + (520u << 10));          // 1 KB
    u64*   csr       = (u64*)(ws + (1u  << 20));           // 8 MB
    float* xf        = (float*)(ws + (9u  << 20));         // 4 MB f32 state
    unsigned short* xb0 = (unsigned short*)(ws + (13u << 20)); // 2 MB bf16 mirror
    unsigned short* xb1 = (unsigned short*)(ws + (15u << 20)); // 2 MB bf16 mirror

    int T = out_size / (B_C * NODES_C);          // = 20
    size_t TN = (size_t)T * NODES_C;

    hipMemsetAsync(hist256, 0, 256 * sizeof(int), stream);
    k_hist   <<<E_C / 1024, 256, 0, stream>>>(dst, hist256);
    k_scan256<<<1, 256, 0, stream>>>(hist256, base256, fill256);
    k_bucket <<<E_C / 4096, 256, 0, stream>>>(src, dst, dist, coeffs, fill256, csr);
    k_sortb  <<<256, 256, 0, stream>>>(base256, hist256, csr, row_start);
    k_init   <<<(NODES_C * B_C) / 256, 256, 0, stream>>>(x_in, xf, xb0);

    unsigned short* xbufs[2] = { xb0, xb1 };
    for (int t = 0; t < T; ++t) {
        k_step<<<NODES_C / 32, 256, 0, stream>>>(
            row_start, csr, xf, xbufs[t & 1], xbufs[(t + 1) & 1],
            out, dt_p, TN, t);
    }
}